// Round 2
// baseline (212.861 us; speedup 1.0000x reference)
//
#include <hip/hip_runtime.h>
#include <stdint.h>

#define BATCH 32
#define CIN   64
#define HH    112
#define WW    112
#define COUT_ 64

typedef int v4i __attribute__((ext_vector_type(4)));

// Kernel 0: narrow int32->int8 and transpose weights [co][ci][kh][kw] ->
// [co][kh][kw][ci] so A-fragments (16 consecutive k = contiguous ci at a
// fixed tap) are direct 8B loads. 36,864 int32 in, 36,864 B out (d_ws).
__global__ void wtrans_kernel(const int* __restrict__ wq, int8_t* __restrict__ wt) {
    int idx = blockIdx.x * 256 + threadIdx.x;   // 0 .. 36863, exact
    int ci   = idx & 63;
    int khkw = (idx >> 6) % 9;
    int co   = idx / 576;
    wt[idx] = (int8_t)wq[co * 576 + ci * 9 + khkw];
}

// Main conv kernel. Block = 256 threads (4 waves), one (b, 2-row) tile.
// LDS holds x rows h0-1..h0+2 transposed+narrowed to [row][col][ci] bytes,
// ci-pitch 72B, cols 0..113 map to input cols -1..112 (zero padded).
__launch_bounds__(256, 2)
__global__ void conv_kernel(const int* __restrict__ x,       // int32-materialized int8
                            const int8_t* __restrict__ wt,
                            const float*  __restrict__ wscale,
                            const float*  __restrict__ ascale,
                            const float*  __restrict__ bias,
                            float*        __restrict__ out) {
    __shared__ int8_t xs[4 * 114 * 72];   // 32,832 B

    const int tid = threadIdx.x;
    const int bt  = blockIdx.x;
    const int b   = bt / 56;
    const int h0  = (bt % 56) * 2;

    // ---- stage x tile: int32 -> int8, transpose w<->ci via v_perm ----
    // 1792 jobs = 4 rows x 28 colgroups x 16 cigroups; 7 per thread.
    // Each job: 4 ci-planes x 4 pixels; int4 (16B) load per ci-plane.
    #pragma unroll
    for (int it = 0; it < 7; ++it) {
        int job = tid + it * 256;
        int ci4 = job & 15;            // ci = ci4*4
        int cg  = (job >> 4) % 28;     // w = cg*4
        int row = job / 448;           // 0..3
        int hh  = h0 - 1 + row;
        v4i q0 = {0,0,0,0}, q1 = {0,0,0,0}, q2 = {0,0,0,0}, q3 = {0,0,0,0};
        if (hh >= 0 && hh < HH) {
            const v4i* gp = (const v4i*)
                (x + ((size_t)(b * CIN + ci4 * 4) * HH + hh) * WW + cg * 4);
            q0 = gp[0];
            q1 = gp[3136];          // +1 ci plane (112*112/4 int4s)
            q2 = gp[2 * 3136];
            q3 = gp[3 * 3136];
        }
        // pack low bytes: out dword j = {lo(q0[j]), lo(q1[j]), lo(q2[j]), lo(q3[j])}
        #pragma unroll
        for (int j = 0; j < 4; ++j) {
            uint32_t lo01 = __builtin_amdgcn_perm((uint32_t)q1[j], (uint32_t)q0[j], 0x0C0C0400u);
            uint32_t lo23 = __builtin_amdgcn_perm((uint32_t)q3[j], (uint32_t)q2[j], 0x04000C0Cu);
            int addr = (row * 114 + cg * 4 + 1 + j) * 72 + ci4 * 4;
            *(uint32_t*)&xs[addr] = lo01 | lo23;
        }
    }
    // zero the padding columns 0 and 113 (input cols -1 and 112)
    if (tid < 128) {
        int ci4 = tid & 15;
        int col = ((tid >> 4) & 1) ? 113 : 0;
        int row = tid >> 5;
        *(uint32_t*)&xs[(row * 114 + col) * 72 + ci4 * 4] = 0u;
    }
    __syncthreads();

    // ---- MFMA main loop ----
    const int lane = tid & 63;
    const int wave = tid >> 6;
    const int ln15 = lane & 15;
    const int quad = lane >> 4;
    const int r    = wave >> 1;        // output row within tile (0/1)
    const int coh  = wave & 1;         // cout half
    const int cobase = coh * 32;

    v4i acc[2][7];
    #pragma unroll
    for (int mt = 0; mt < 2; ++mt)
        #pragma unroll
        for (int nt = 0; nt < 7; ++nt)
            acc[mt][nt] = (v4i){0, 0, 0, 0};

    // A rows: wt[co][k], k = (kh*3+kw)*64 + ci ; frag = 8B at k = kc*32+quad*8
    const long* w64a = (const long*)(wt + (size_t)(cobase + ln15) * 576);
    const long* w64b = (const long*)(wt + (size_t)(cobase + 16 + ln15) * 576);

    #pragma unroll
    for (int kc = 0; kc < 18; ++kc) {
        const int khkw = kc >> 1;
        const int kh   = khkw / 3;
        const int kw   = khkw % 3;
        const int half = kc & 1;
        long a0 = w64a[kc * 4 + quad];
        long a1 = w64b[kc * 4 + quad];
        const int rowb  = (kh + r) * 114;
        const int cioff = half * 32 + quad * 8;
        #pragma unroll
        for (int nt = 0; nt < 7; ++nt) {
            int col = nt * 16 + ln15 + kw;   // = w + kw - 1, shifted by +1 pad
            long bfrag = *(const long*)&xs[(rowb + col) * 72 + cioff];
            acc[0][nt] = __builtin_amdgcn_mfma_i32_16x16x32_i8(a0, bfrag, acc[0][nt], 0, 0, 0);
            acc[1][nt] = __builtin_amdgcn_mfma_i32_16x16x32_i8(a1, bfrag, acc[1][nt], 0, 0, 0);
        }
    }

    // ---- fused dequant + bias epilogue ----
    const float s = ascale[0] * wscale[0];
    const int h = h0 + r;
    #pragma unroll
    for (int mt = 0; mt < 2; ++mt) {
        #pragma unroll
        for (int reg = 0; reg < 4; ++reg) {
            int co = cobase + mt * 16 + quad * 4 + reg;   // C/D: row = quad*4+reg
            float bv = bias[co];
            float* op = out + ((size_t)(b * COUT_ + co) * HH + h) * WW;
            #pragma unroll
            for (int nt = 0; nt < 7; ++nt) {
                int wp = nt * 16 + ln15;                  // C/D: col = lane&15
                op[wp] = (float)acc[mt][nt][reg] * s + bv;
            }
        }
    }
}

extern "C" void kernel_launch(void* const* d_in, const int* in_sizes, int n_in,
                              void* d_out, int out_size, void* d_ws, size_t ws_size,
                              hipStream_t stream) {
    const int*    xq     = (const int*)d_in[0];
    const int*    wq     = (const int*)d_in[1];
    const float*  wscale = (const float*)d_in[2];
    const float*  ascale = (const float*)d_in[3];
    const float*  bias   = (const float*)d_in[4];
    int8_t* wt  = (int8_t*)d_ws;          // needs 36,864 B of scratch
    float*  out = (float*)d_out;

    wtrans_kernel<<<144, 256, 0, stream>>>(wq, wt);
    conv_kernel<<<BATCH * 56, 256, 0, stream>>>(xq, wt, wscale, ascale, bias, out);
}